// Round 6
// baseline (1782.156 us; speedup 1.0000x reference)
//
#include <hip/hip_runtime.h>
#include <hip/hip_bf16.h>
#include <cstdint>

// Problem constants
#define NROWS 65536
#define TTREAT 2

typedef __bf16 bf16x8 __attribute__((ext_vector_type(8)));
typedef float f32x4 __attribute__((ext_vector_type(4)));
typedef unsigned short u16;
typedef u16 u16x8 __attribute__((ext_vector_type(8)));

#define GLOBAL_AS __attribute__((address_space(1)))
#define LDS_AS __attribute__((address_space(3)))

// ---------------------------------------------------------------------------
// XOR-swizzled bf16 layout: every self-produced [rows,K] bf16 buffer stores
// the 16B chunk j (8 elems) of each 64-elem K-group at position j ^ (row&7).
// Kills the 16-way LDS bank conflict of the 128B-row-stride fragment reads
// (verified: SQ_LDS_BANK_CONFLICT == 0 in rocprof).
// ---------------------------------------------------------------------------
__device__ __forceinline__ int swz_col(int col, int row) {
    return (col & ~63) | (((((col >> 3) & 7) ^ (row & 7)) << 3)) | (col & 7);
}

__device__ __forceinline__ u16 f32_to_bf16_bits(float f) {
    union { float f; uint32_t u; } v; v.f = f;
    uint32_t u = v.u;
    return (u16)((u + 0x7FFFu + ((u >> 16) & 1u)) >> 16);
}

// ---------------- conversion: f32 -> swizzled bf16 (one 16B chunk/thread) ----
// K must be 512 here (row = chunk>>6).
__global__ void cvt_f32_bf16(const float4* __restrict__ src, u16x8* __restrict__ dst, int n8) {
    int i = blockIdx.x * blockDim.x + threadIdx.x;
    if (i >= n8) return;
    float4 a = src[2 * i], b = src[2 * i + 1];
    u16x8 r;
    r[0] = f32_to_bf16_bits(a.x); r[1] = f32_to_bf16_bits(a.y);
    r[2] = f32_to_bf16_bits(a.z); r[3] = f32_to_bf16_bits(a.w);
    r[4] = f32_to_bf16_bits(b.x); r[5] = f32_to_bf16_bits(b.y);
    r[6] = f32_to_bf16_bits(b.z); r[7] = f32_to_bf16_bits(b.w);
    int row = i >> 6;                                   // K=512 -> 64 chunks/row
    int j = (i & ~7) | ((i ^ row) & 7);                 // swizzle chunk in group
    dst[j] = r;
}

// ---------------- weight transpose: src [K,M] f32 -> dst [M,K] bf16 swizzled -
__global__ void transpose_w(const float* __restrict__ src, u16* __restrict__ dst, int K, int M) {
    __shared__ float tile[32][33];
    size_t boff = (size_t)blockIdx.z * K * M;
    src += boff; dst += boff;
    int m0 = blockIdx.x * 32, k0 = blockIdx.y * 32;
    int tx = threadIdx.x, ty = threadIdx.y;
#pragma unroll
    for (int i = 0; i < 32; i += 8)
        tile[ty + i][tx] = src[(size_t)(k0 + ty + i) * M + m0 + tx];
    __syncthreads();
#pragma unroll
    for (int i = 0; i < 32; i += 8) {
        int row = m0 + ty + i, col = k0 + tx;
        dst[(size_t)row * K + swz_col(col, row)] = f32_to_bf16_bits(tile[tx][ty + i]);
    }
}

// ---------------- partition rows by treatment --------------------------------
__global__ void zero_cnt(int* cnt) {
    if (threadIdx.x < TTREAT) cnt[threadIdx.x] = 0;
}

// Hierarchical: wave ballot -> LDS wave counts -> 1 atomic/treatment/block.
__global__ void partition_rows(const int* __restrict__ treat, int* __restrict__ idx, int* __restrict__ cnt) {
    __shared__ int waveCnt1[4];
    __shared__ int blockBase[2];
    const int tid = threadIdx.x;
    const int i = blockIdx.x * 256 + tid;
    const int wave = tid >> 6, lane = tid & 63;
    const int t = treat[i];
    const unsigned long long m1 = __ballot(t == 1);
    const int n1 = __popcll(m1);
    if (lane == 0) waveCnt1[wave] = n1;
    __syncthreads();
    const int w0 = waveCnt1[0], w1 = waveCnt1[1], w2 = waveCnt1[2], w3 = waveCnt1[3];
    const int tot1 = w0 + w1 + w2 + w3;
    if (tid == 0) blockBase[0] = atomicAdd(&cnt[0], 256 - tot1);
    else if (tid == 64) blockBase[1] = atomicAdd(&cnt[1], tot1);
    __syncthreads();
    int waveOff1 = 0;
    if (wave > 0) waveOff1 += w0;
    if (wave > 1) waveOff1 += w1;
    if (wave > 2) waveOff1 += w2;
    const int below1 = (int)__popcll(m1 & ((1ull << lane) - 1ull));
    int pos;
    if (t == 1) pos = blockBase[1] + waveOff1 + below1;
    else        pos = blockBase[0] + (wave * 64 - waveOff1) + (lane - below1);
    idx[t * NROWS + pos] = i;
}

// ---------------- output init: y[i] = bo[treat[i]], t_out[i] = 1.0 -----------
// (softmax over size-1 axis == 1 exactly; head bias folded into y init so the
// fused-head epilogue only atomicAdds partial dots.)
__global__ void init_outputs(const int* __restrict__ treat, const float* __restrict__ bo,
                             float* __restrict__ y, float* __restrict__ t_out) {
    int i = blockIdx.x * 256 + threadIdx.x;
    if (i < NROWS) { y[i] = bo[treat[i]]; t_out[i] = 1.0f; }
}

// ---------------- main GEMM: C = relu(A @ Bt^T + bias) -----------------------
// All bf16 buffers (A, Bt, C) use the swizzled layout. C32 (f32) is logical.
// LDS invariant: slot s of LDS row r holds logical chunk s ^ (r&7).
// FUSE_HEAD: no C write; instead per-row partial dot with Wo over this block's
// 128 cols, reduced across lanes (width-16 shfl matches C-layout col=l16),
// atomicAdd'ed into y[idx[row]]. 8 atomics/row total, distinct addresses.
// 128x128 tile, BK=64, 256 threads (4 waves as 2x2 of 64x64).
//
// T3-minimum 2-phase pipeline (m248 recipe): double-buffered LDS; per K-step
// {issue stage(s+1) -> other buf; ds_read+32xMFMA from current buf;
// __syncthreads()}. The sync's implicit vmcnt(0) drain lands AFTER compute,
// so the staging flight time overlaps the MFMAs (previous serial structure:
// stage -> drain -> compute, zero intra-block overlap). LDS 64 KiB -> 2
// blocks/CU (was 5); intra-block overlap replaces the lost TLP.
//
// XCD-aware bijective block remap (m204 formula): each XCD gets a CONTIGUOUS
// chunk of the row-major block space, so all col-blocks of a row-panel run
// on one XCD and share its L2.
template <bool GATHER, bool WRITE_F32, bool FUSE_HEAD>
__global__ void gemm_bias_relu(const u16* __restrict__ A, const u16* __restrict__ Bt,
                               const float* __restrict__ bias,
                               u16* __restrict__ C, float* __restrict__ C32,
                               const int* __restrict__ idx, const int* __restrict__ cntp,
                               int nrows, int chunkStart, int maxRows, int K, int M,
                               const float* __restrict__ Wo, float* __restrict__ y) {
    int rows = (cntp ? *cntp : nrows) - chunkStart;
    if (rows > maxRows) rows = maxRows;

    // bijective XCD remap: xcd chunk = [start(xcd), start(xcd)+len(xcd))
    const unsigned gx  = gridDim.x;
    const unsigned nwg = gx * gridDim.y;
    const unsigned lin = blockIdx.y * gx + blockIdx.x;
    const unsigned q = nwg >> 3, r = nwg & 7;
    const unsigned xcd = lin & 7, ii = lin >> 3;
    const unsigned wg = (xcd < r ? xcd * (q + 1) : r * (q + 1) + (xcd - r) * q) + ii;

    int rowBase = (int)(wg / gx) * 128;
    if (rows <= 0 || rowBase >= rows) return;
    int colBase = (int)(wg % gx) * 128;

    __shared__ __align__(16) u16 As[2][128 * 64];
    __shared__ __align__(16) u16 Bs[2][128 * 64];

    const int tid = threadIdx.x;
    const int wave = tid >> 6, lane = tid & 63;
    const int quad = lane >> 4, l16 = lane & 15;
    const int wm = wave >> 1, wn = wave & 1;

    // staging geometry: lane handles row r0 (8 lanes/row), chunk (tid&7)
    const int r0 = tid >> 3;          // 0..31 (local row within 32-row slab)
    const int kc = (tid & 7) * 8;     // logical-position chunk offset 0..56

    size_t a_off[4], b_off[4];
#pragma unroll
    for (int it = 0; it < 4; ++it) {
        int r_ = rowBase + r0 + it * 32;
        if (GATHER) {
            int rc = r_ < rows ? r_ : (rows - 1);
            int g = idx[rc];
            // fetch logical chunk (slot ^ (r&7)), stored at position ^ (g&7):
            int kcg = ((((tid & 7) ^ (r_ & 7) ^ (g & 7)) & 7) * 8);
            a_off[it] = (size_t)g * K + kcg;
        } else {
            // physical parity == local parity: fetch position (tid&7) verbatim
            a_off[it] = (size_t)r_ * K + kc;
        }
        int c = colBase + r0 + it * 32;   // always < M (M multiple of 128)
        b_off[it] = (size_t)c * K + kc;
    }

#define STAGE_TILE(buf, k0_)                                                   \
    do {                                                                       \
        _Pragma("unroll")                                                      \
        for (int it = 0; it < 4; ++it) {                                       \
            __builtin_amdgcn_global_load_lds(                                  \
                (const GLOBAL_AS void*)(A + a_off[it] + (k0_)),                \
                (LDS_AS void*)(&As[buf][(it * 256 + wave * 64) * 8]), 16, 0, 0);\
            __builtin_amdgcn_global_load_lds(                                  \
                (const GLOBAL_AS void*)(Bt + b_off[it] + (k0_)),               \
                (LDS_AS void*)(&Bs[buf][(it * 256 + wave * 64) * 8]), 16, 0, 0);\
        }                                                                      \
    } while (0)

    f32x4 acc[4][4] = {};
    const int NS = K >> 6;

    // prologue: stage tile 0 -> buf 0; drain; then 2-phase steady state
    STAGE_TILE(0, 0);
    __syncthreads();

    for (int s = 0; s < NS; ++s) {
        const int cb = s & 1;
        if (s + 1 < NS) STAGE_TILE(cb ^ 1, (s + 1) << 6);   // issue-ahead
#pragma unroll
        for (int kk = 0; kk < 2; ++kk) {
            bf16x8 aF[4], bF[4];
            // logical chunk kk*4+quad lives at slot (kk*4+quad) ^ (row&7);
            // row&7 == l16&7 for every fragment row (row = base16*16 + l16).
            const int csw = ((kk * 4 + quad) ^ (l16 & 7)) * 8;
#pragma unroll
            for (int mi = 0; mi < 4; ++mi)
                aF[mi] = *(const bf16x8*)&As[cb][(wm * 64 + mi * 16 + l16) * 64 + csw];
#pragma unroll
            for (int ni = 0; ni < 4; ++ni)
                bF[ni] = *(const bf16x8*)&Bs[cb][(wn * 64 + ni * 16 + l16) * 64 + csw];
#pragma unroll
            for (int mi = 0; mi < 4; ++mi)
#pragma unroll
                for (int ni = 0; ni < 4; ++ni)
                    acc[mi][ni] = __builtin_amdgcn_mfma_f32_16x16x32_bf16(
                        aF[mi], bF[ni], acc[mi][ni], 0, 0, 0);
        }
        // drains vmcnt(0) (stage s+1 landed) + lgkm, and orders LDS reuse:
        // buf[cb] readers done before iter s+1 re-stages into buf[cb].
        __syncthreads();
    }
#undef STAGE_TILE

    // epilogue: bias + relu
    float bv[4];
#pragma unroll
    for (int ni = 0; ni < 4; ++ni) bv[ni] = bias[colBase + wn * 64 + ni * 16 + l16];

    if (FUSE_HEAD) {
        float wv[4];
#pragma unroll
        for (int ni = 0; ni < 4; ++ni) wv[ni] = Wo[colBase + wn * 64 + ni * 16 + l16];
        float hs[4][4];   // [mi][r] per-lane partial dot over this lane's 4 cols
#pragma unroll
        for (int mi = 0; mi < 4; ++mi)
#pragma unroll
            for (int r_ = 0; r_ < 4; ++r_) {
                float s = 0.f;
#pragma unroll
                for (int ni = 0; ni < 4; ++ni) {
                    float v = acc[mi][ni][r_] + bv[ni];
                    v = v > 0.f ? v : 0.f;
                    s += v * wv[ni];
                }
                hs[mi][r_] = s;
            }
        // reduce across the 16 lanes of each quad (C-layout: col = l16)
#pragma unroll
        for (int mi = 0; mi < 4; ++mi)
#pragma unroll
            for (int r_ = 0; r_ < 4; ++r_) {
                float s = hs[mi][r_];
                s += __shfl_down(s, 8, 16);
                s += __shfl_down(s, 4, 16);
                s += __shfl_down(s, 2, 16);
                s += __shfl_down(s, 1, 16);
                if (l16 == 0) {
                    int row = rowBase + wm * 64 + mi * 16 + quad * 4 + r_;
                    if (row < rows) atomicAdd(&y[idx[row]], s);
                }
            }
    } else {
#pragma unroll
        for (int mi = 0; mi < 4; ++mi) {
            int rloc = rowBase + wm * 64 + mi * 16 + quad * 4;
#pragma unroll
            for (int ni = 0; ni < 4; ++ni) {
                int col = colBase + wn * 64 + ni * 16 + l16;
#pragma unroll
                for (int r_ = 0; r_ < 4; ++r_) {
                    int row = rloc + r_;
                    if (row < rows) {
                        float v = acc[mi][ni][r_] + bv[ni];
                        v = v > 0.f ? v : 0.f;
                        C[(size_t)row * M + swz_col(col, row)] = f32_to_bf16_bits(v);
                        if (WRITE_F32) C32[(size_t)row * M + col] = v;
                    }
                }
            }
        }
    }
}

extern "C" void kernel_launch(void* const* d_in, const int* in_sizes, int n_in,
                              void* d_out, int out_size, void* d_ws, size_t ws_size,
                              hipStream_t stream) {
    const float* x   = (const float*)d_in[0];
    const int* treat = (const int*)d_in[1];
    const float* Wx0 = (const float*)d_in[2];
    const float* bx0 = (const float*)d_in[3];
    const float* Wx1 = (const float*)d_in[4];
    const float* bx1 = (const float*)d_in[5];
    const float* Wx2 = (const float*)d_in[6];
    const float* bx2 = (const float*)d_in[7];
    const float* Wy0 = (const float*)d_in[8];
    const float* by0 = (const float*)d_in[9];
    const float* Wy1 = (const float*)d_in[10];
    const float* by1 = (const float*)d_in[11];
    const float* Wo  = (const float*)d_in[12];
    const float* bo  = (const float*)d_in[13];
    // Wt (14), bt (15) unused: softmax over size-1 axis == 1 exactly

    float* out_y  = (float*)d_out;                       // [N]
    float* out_xe = out_y + NROWS;                       // [N, 512]
    float* out_t  = out_xe + (size_t)NROWS * 512;        // [N]

    // ---- choose row-chunk size R from ws_size (deterministic per process) ----
    const size_t FIXED = ((size_t)(2048 * 512 + 2048 * 2048 + 512 * 2048
                          + TTREAT * 1024 * 512 + TTREAT * 512 * 1024
                          + (size_t)NROWS * 512) * 2)                 // bf16 bufs
                          + (size_t)TTREAT * NROWS * 4 + (1 << 20);   // idx + slack
    int R = 512;
    const int cands[8] = {65536, 32768, 16384, 8192, 4096, 2048, 1024, 512};
    for (int ci = 0; ci < 8; ++ci) {
        // variable/row: xbc 1024 + h1c 4096 + h2c 4096 + g1c 2048 = 11264 B
        if (FIXED + (size_t)cands[ci] * 11264 <= ws_size) { R = cands[ci]; break; }
    }
    const int NCHUNK = NROWS / R;

    // ---- workspace carve-up ----
    size_t off = 0;
    auto carve = [&](size_t bytes) {
        void* p = (char*)d_ws + off;
        off += (bytes + 255) & ~(size_t)255;
        return p;
    };
    u16* Wx0t = (u16*)carve((size_t)2048 * 512 * 2);
    u16* Wx1t = (u16*)carve((size_t)2048 * 2048 * 2);
    u16* Wx2t = (u16*)carve((size_t)512 * 2048 * 2);
    u16* Wy0t = (u16*)carve((size_t)TTREAT * 1024 * 512 * 2);
    u16* Wy1t = (u16*)carve((size_t)TTREAT * 512 * 1024 * 2);
    u16* xe   = (u16*)carve((size_t)NROWS * 512 * 2);        // full-N bf16 x_emb
    int* idx  = (int*)carve((size_t)TTREAT * NROWS * 4);
    int* cnt  = (int*)carve(256);
    u16* xbc  = (u16*)carve((size_t)R * 512 * 2);            // chunk x bf16
    u16* h1c  = (u16*)carve((size_t)R * 2048 * 2);
    u16* h2c  = (u16*)carve((size_t)R * 2048 * 2);
    u16* g1c  = (u16*)carve((size_t)R * 1024 * 2);

    dim3 tb32(32, 8);

    // weight transposes (bf16, [M,K], swizzled) — once
    transpose_w<<<dim3(2048 / 32, 512 / 32, 1), tb32, 0, stream>>>(Wx0, Wx0t, 512, 2048);
    transpose_w<<<dim3(2048 / 32, 2048 / 32, 1), tb32, 0, stream>>>(Wx1, Wx1t, 2048, 2048);
    transpose_w<<<dim3(512 / 32, 2048 / 32, 1), tb32, 0, stream>>>(Wx2, Wx2t, 2048, 512);
    transpose_w<<<dim3(1024 / 32, 512 / 32, TTREAT), tb32, 0, stream>>>(Wy0, Wy0t, 512, 1024);
    transpose_w<<<dim3(512 / 32, 1024 / 32, TTREAT), tb32, 0, stream>>>(Wy1, Wy1t, 1024, 512);

    // partition rows by treatment — once
    zero_cnt<<<1, 64, 0, stream>>>(cnt);
    partition_rows<<<NROWS / 256, 256, 0, stream>>>(treat, idx, cnt);

    // output init (y = head bias, t_out = 1.0)
    init_outputs<<<NROWS / 256, 256, 0, stream>>>(treat, bo, out_y, out_t);

    const int gy = R / 128;   // chunk-local row blocks

    // ---- trunk, chunked over rows ----
    for (int c = 0; c < NCHUNK; ++c) {
        int cS = c * R;
        cvt_f32_bf16<<<(R * 512 / 8 + 255) / 256, 256, 0, stream>>>(
            (const float4*)(x + (size_t)cS * 512), (u16x8*)xbc, R * 512 / 8);
        gemm_bias_relu<false, false, false><<<dim3(2048 / 128, gy), 256, 0, stream>>>(
            xbc, Wx0t, bx0, h1c, nullptr, nullptr, nullptr, NROWS, cS, R, 512, 2048,
            nullptr, nullptr);
        gemm_bias_relu<false, false, false><<<dim3(2048 / 128, gy), 256, 0, stream>>>(
            h1c, Wx1t, bx1, h2c, nullptr, nullptr, nullptr, NROWS, cS, R, 2048, 2048,
            nullptr, nullptr);
        gemm_bias_relu<false, true, false><<<dim3(512 / 128, gy), 256, 0, stream>>>(
            h2c, Wx2t, bx2, xe + (size_t)cS * 512, out_xe + (size_t)cS * 512,
            nullptr, nullptr, NROWS, cS, R, 2048, 512, nullptr, nullptr);
    }

    // ---- experts (only the selected treatment's rows), chunked ----
    for (int t = 0; t < TTREAT; ++t) {
        const int* idx_t = idx + (size_t)t * NROWS;
        for (int c = 0; c < NCHUNK; ++c) {
            int cS = c * R;
            gemm_bias_relu<true, false, false><<<dim3(1024 / 128, gy), 256, 0, stream>>>(
                xe, Wy0t + (size_t)t * 1024 * 512, by0 + (size_t)t * 1024,
                g1c, nullptr, idx_t + cS, cnt + t, NROWS, cS, R, 512, 1024,
                nullptr, nullptr);
            // expert layer 1 with fused output head (no C write; atomic dots)
            gemm_bias_relu<false, false, true><<<dim3(512 / 128, gy), 256, 0, stream>>>(
                g1c, Wy1t + (size_t)t * 512 * 1024, by1 + (size_t)t * 512,
                nullptr, nullptr, idx_t + cS, cnt + t, NROWS, cS, R, 1024, 512,
                Wo + (size_t)t * 512, out_y);
        }
    }
}

// Round 7
// 1394.775 us; speedup vs baseline: 1.2777x; 1.2777x over previous
//
#include <hip/hip_runtime.h>
#include <hip/hip_bf16.h>
#include <cstdint>

// Problem constants
#define NROWS 65536
#define TTREAT 2

typedef __bf16 bf16x8 __attribute__((ext_vector_type(8)));
typedef float f32x4 __attribute__((ext_vector_type(4)));
typedef unsigned short u16;
typedef u16 u16x8 __attribute__((ext_vector_type(8)));

#define GLOBAL_AS __attribute__((address_space(1)))
#define LDS_AS __attribute__((address_space(3)))

// ---------------------------------------------------------------------------
// XOR-swizzled bf16 layout: every self-produced [rows,K] bf16 buffer stores
// the 16B chunk j (8 elems) of each 64-elem K-group at position j ^ (row&7).
// Kills the 16-way LDS bank conflict of the 128B-row-stride fragment reads
// (verified: SQ_LDS_BANK_CONFLICT == 0 in rocprof).
// ---------------------------------------------------------------------------
__device__ __forceinline__ int swz_col(int col, int row) {
    return (col & ~63) | (((((col >> 3) & 7) ^ (row & 7)) << 3)) | (col & 7);
}

__device__ __forceinline__ u16 f32_to_bf16_bits(float f) {
    union { float f; uint32_t u; } v; v.f = f;
    uint32_t u = v.u;
    return (u16)((u + 0x7FFFu + ((u >> 16) & 1u)) >> 16);
}

// ---------------- conversion: f32 -> swizzled bf16 (one 16B chunk/thread) ----
// K must be 512 here (row = chunk>>6).
__global__ void cvt_f32_bf16(const float4* __restrict__ src, u16x8* __restrict__ dst, int n8) {
    int i = blockIdx.x * blockDim.x + threadIdx.x;
    if (i >= n8) return;
    float4 a = src[2 * i], b = src[2 * i + 1];
    u16x8 r;
    r[0] = f32_to_bf16_bits(a.x); r[1] = f32_to_bf16_bits(a.y);
    r[2] = f32_to_bf16_bits(a.z); r[3] = f32_to_bf16_bits(a.w);
    r[4] = f32_to_bf16_bits(b.x); r[5] = f32_to_bf16_bits(b.y);
    r[6] = f32_to_bf16_bits(b.z); r[7] = f32_to_bf16_bits(b.w);
    int row = i >> 6;                                   // K=512 -> 64 chunks/row
    int j = (i & ~7) | ((i ^ row) & 7);                 // swizzle chunk in group
    dst[j] = r;
}

// ---------------- weight transpose: src [K,M] f32 -> dst [M,K] bf16 swizzled -
__global__ void transpose_w(const float* __restrict__ src, u16* __restrict__ dst, int K, int M) {
    __shared__ float tile[32][33];
    size_t boff = (size_t)blockIdx.z * K * M;
    src += boff; dst += boff;
    int m0 = blockIdx.x * 32, k0 = blockIdx.y * 32;
    int tx = threadIdx.x, ty = threadIdx.y;
#pragma unroll
    for (int i = 0; i < 32; i += 8)
        tile[ty + i][tx] = src[(size_t)(k0 + ty + i) * M + m0 + tx];
    __syncthreads();
#pragma unroll
    for (int i = 0; i < 32; i += 8) {
        int row = m0 + ty + i, col = k0 + tx;
        dst[(size_t)row * K + swz_col(col, row)] = f32_to_bf16_bits(tile[tx][ty + i]);
    }
}

// ---------------- partition rows by treatment --------------------------------
__global__ void zero_cnt(int* cnt) {
    if (threadIdx.x < TTREAT) cnt[threadIdx.x] = 0;
}

// Hierarchical: wave ballot -> LDS wave counts -> 1 atomic/treatment/block.
__global__ void partition_rows(const int* __restrict__ treat, int* __restrict__ idx, int* __restrict__ cnt) {
    __shared__ int waveCnt1[4];
    __shared__ int blockBase[2];
    const int tid = threadIdx.x;
    const int i = blockIdx.x * 256 + tid;
    const int wave = tid >> 6, lane = tid & 63;
    const int t = treat[i];
    const unsigned long long m1 = __ballot(t == 1);
    const int n1 = __popcll(m1);
    if (lane == 0) waveCnt1[wave] = n1;
    __syncthreads();
    const int w0 = waveCnt1[0], w1 = waveCnt1[1], w2 = waveCnt1[2], w3 = waveCnt1[3];
    const int tot1 = w0 + w1 + w2 + w3;
    if (tid == 0) blockBase[0] = atomicAdd(&cnt[0], 256 - tot1);
    else if (tid == 64) blockBase[1] = atomicAdd(&cnt[1], tot1);
    __syncthreads();
    int waveOff1 = 0;
    if (wave > 0) waveOff1 += w0;
    if (wave > 1) waveOff1 += w1;
    if (wave > 2) waveOff1 += w2;
    const int below1 = (int)__popcll(m1 & ((1ull << lane) - 1ull));
    int pos;
    if (t == 1) pos = blockBase[1] + waveOff1 + below1;
    else        pos = blockBase[0] + (wave * 64 - waveOff1) + (lane - below1);
    idx[t * NROWS + pos] = i;
}

// ---------------- output init: y[i] = bo[treat[i]], t_out[i] = 1.0 -----------
// (softmax over size-1 axis == 1 exactly; head bias folded into y init so the
// fused-head epilogue only atomicAdds partial dots.)
__global__ void init_outputs(const int* __restrict__ treat, const float* __restrict__ bo,
                             float* __restrict__ y, float* __restrict__ t_out) {
    int i = blockIdx.x * 256 + threadIdx.x;
    if (i < NROWS) { y[i] = bo[treat[i]]; t_out[i] = 1.0f; }
}

// ---------------- main GEMM: C = relu(A @ Bt^T + bias) -----------------------
// All bf16 buffers (A, Bt, C) use the swizzled layout. C32 (f32) is logical.
// LDS invariant: slot s of LDS row r holds logical chunk s ^ (r&7).
// FUSE_HEAD: no C write; instead per-row partial dot with Wo over this block's
// 128 cols, reduced across lanes (width-16 shfl matches C-layout col=l16),
// atomicAdd'ed into y[idx[row]]. 8 atomics/row total, distinct addresses.
// 128x128 tile, BK=64, 256 threads (4 waves as 2x2 of 64x64).
//
// Session-verified structure (R4 = best measured): serial sync->stage->drain->
// compute at 32 KiB LDS = 5 blocks/CU. All pipelined variants (8-phase 256²
// R1-R3; 2-phase dbuf R6) LOSE because they cut resident blocks — occupancy
// TLP is the dominant latency hider on this problem. Do not re-trade LDS for
// pipelining without new evidence.
//
// XCD-aware bijective block remap (m204 formula): each XCD gets a CONTIGUOUS
// chunk of the row-major block space, so all col-blocks of a row-panel run
// on one XCD and share its L2.
template <bool GATHER, bool WRITE_F32, bool FUSE_HEAD>
__global__ void gemm_bias_relu(const u16* __restrict__ A, const u16* __restrict__ Bt,
                               const float* __restrict__ bias,
                               u16* __restrict__ C, float* __restrict__ C32,
                               const int* __restrict__ idx, const int* __restrict__ cntp,
                               int nrows, int chunkStart, int maxRows, int K, int M,
                               const float* __restrict__ Wo, float* __restrict__ y) {
    int rows = (cntp ? *cntp : nrows) - chunkStart;
    if (rows > maxRows) rows = maxRows;

    // bijective XCD remap: xcd chunk = [start(xcd), start(xcd)+len(xcd))
    const unsigned gx  = gridDim.x;
    const unsigned nwg = gx * gridDim.y;
    const unsigned lin = blockIdx.y * gx + blockIdx.x;
    const unsigned q = nwg >> 3, r = nwg & 7;
    const unsigned xcd = lin & 7, ii = lin >> 3;
    const unsigned wg = (xcd < r ? xcd * (q + 1) : r * (q + 1) + (xcd - r) * q) + ii;

    int rowBase = (int)(wg / gx) * 128;
    if (rows <= 0 || rowBase >= rows) return;
    int colBase = (int)(wg % gx) * 128;

    __shared__ __align__(16) u16 As[128 * 64];
    __shared__ __align__(16) u16 Bs[128 * 64];

    const int tid = threadIdx.x;
    const int wave = tid >> 6, lane = tid & 63;
    const int quad = lane >> 4, l16 = lane & 15;
    const int wm = wave >> 1, wn = wave & 1;

    // staging geometry: lane handles row r0 (8 lanes/row), chunk (tid&7)
    const int r0 = tid >> 3;          // 0..31 (local row within 32-row slab)
    const int kc = (tid & 7) * 8;     // logical-position chunk offset 0..56

    size_t a_off[4], b_off[4];
#pragma unroll
    for (int it = 0; it < 4; ++it) {
        int r_ = rowBase + r0 + it * 32;
        if (GATHER) {
            int rc = r_ < rows ? r_ : (rows - 1);
            int g = idx[rc];
            // fetch logical chunk (slot ^ (r&7)), stored at position ^ (g&7):
            int kcg = ((((tid & 7) ^ (r_ & 7) ^ (g & 7)) & 7) * 8);
            a_off[it] = (size_t)g * K + kcg;
        } else {
            // physical parity == local parity: fetch position (tid&7) verbatim
            a_off[it] = (size_t)r_ * K + kc;
        }
        int c = colBase + r0 + it * 32;   // always < M (M multiple of 128)
        b_off[it] = (size_t)c * K + kc;
    }

    f32x4 acc[4][4] = {};

    for (int k0 = 0; k0 < K; k0 += 64) {
        __syncthreads();
#pragma unroll
        for (int it = 0; it < 4; ++it) {
            __builtin_amdgcn_global_load_lds(
                (const GLOBAL_AS void*)(A + a_off[it] + k0),
                (LDS_AS void*)(&As[(it * 256 + wave * 64) * 8]), 16, 0, 0);
            __builtin_amdgcn_global_load_lds(
                (const GLOBAL_AS void*)(Bt + b_off[it] + k0),
                (LDS_AS void*)(&Bs[(it * 256 + wave * 64) * 8]), 16, 0, 0);
        }
        __syncthreads();
#pragma unroll
        for (int kk = 0; kk < 2; ++kk) {
            bf16x8 aF[4], bF[4];
            // logical chunk kk*4+quad lives at slot (kk*4+quad) ^ (row&7);
            // row&7 == l16&7 for every fragment row (row = base16*16 + l16).
            const int csw = ((kk * 4 + quad) ^ (l16 & 7)) * 8;
#pragma unroll
            for (int mi = 0; mi < 4; ++mi)
                aF[mi] = *(const bf16x8*)&As[(wm * 64 + mi * 16 + l16) * 64 + csw];
#pragma unroll
            for (int ni = 0; ni < 4; ++ni)
                bF[ni] = *(const bf16x8*)&Bs[(wn * 64 + ni * 16 + l16) * 64 + csw];
#pragma unroll
            for (int mi = 0; mi < 4; ++mi)
#pragma unroll
                for (int ni = 0; ni < 4; ++ni)
                    acc[mi][ni] = __builtin_amdgcn_mfma_f32_16x16x32_bf16(
                        aF[mi], bF[ni], acc[mi][ni], 0, 0, 0);
        }
    }

    // epilogue: bias + relu
    float bv[4];
#pragma unroll
    for (int ni = 0; ni < 4; ++ni) bv[ni] = bias[colBase + wn * 64 + ni * 16 + l16];

    if (FUSE_HEAD) {
        float wv[4];
#pragma unroll
        for (int ni = 0; ni < 4; ++ni) wv[ni] = Wo[colBase + wn * 64 + ni * 16 + l16];
        float hs[4][4];   // [mi][r] per-lane partial dot over this lane's 4 cols
#pragma unroll
        for (int mi = 0; mi < 4; ++mi)
#pragma unroll
            for (int r_ = 0; r_ < 4; ++r_) {
                float s = 0.f;
#pragma unroll
                for (int ni = 0; ni < 4; ++ni) {
                    float v = acc[mi][ni][r_] + bv[ni];
                    v = v > 0.f ? v : 0.f;
                    s += v * wv[ni];
                }
                hs[mi][r_] = s;
            }
        // reduce across the 16 lanes of each quad (C-layout: col = l16)
#pragma unroll
        for (int mi = 0; mi < 4; ++mi)
#pragma unroll
            for (int r_ = 0; r_ < 4; ++r_) {
                float s = hs[mi][r_];
                s += __shfl_down(s, 8, 16);
                s += __shfl_down(s, 4, 16);
                s += __shfl_down(s, 2, 16);
                s += __shfl_down(s, 1, 16);
                if (l16 == 0) {
                    int row = rowBase + wm * 64 + mi * 16 + quad * 4 + r_;
                    if (row < rows) atomicAdd(&y[idx[row]], s);
                }
            }
    } else {
#pragma unroll
        for (int mi = 0; mi < 4; ++mi) {
            int rloc = rowBase + wm * 64 + mi * 16 + quad * 4;
#pragma unroll
            for (int ni = 0; ni < 4; ++ni) {
                int col = colBase + wn * 64 + ni * 16 + l16;
#pragma unroll
                for (int r_ = 0; r_ < 4; ++r_) {
                    int row = rloc + r_;
                    if (row < rows) {
                        float v = acc[mi][ni][r_] + bv[ni];
                        v = v > 0.f ? v : 0.f;
                        C[(size_t)row * M + swz_col(col, row)] = f32_to_bf16_bits(v);
                        if (WRITE_F32) C32[(size_t)row * M + col] = v;
                    }
                }
            }
        }
    }
}

extern "C" void kernel_launch(void* const* d_in, const int* in_sizes, int n_in,
                              void* d_out, int out_size, void* d_ws, size_t ws_size,
                              hipStream_t stream) {
    const float* x   = (const float*)d_in[0];
    const int* treat = (const int*)d_in[1];
    const float* Wx0 = (const float*)d_in[2];
    const float* bx0 = (const float*)d_in[3];
    const float* Wx1 = (const float*)d_in[4];
    const float* bx1 = (const float*)d_in[5];
    const float* Wx2 = (const float*)d_in[6];
    const float* bx2 = (const float*)d_in[7];
    const float* Wy0 = (const float*)d_in[8];
    const float* by0 = (const float*)d_in[9];
    const float* Wy1 = (const float*)d_in[10];
    const float* by1 = (const float*)d_in[11];
    const float* Wo  = (const float*)d_in[12];
    const float* bo  = (const float*)d_in[13];
    // Wt (14), bt (15) unused: softmax over size-1 axis == 1 exactly

    float* out_y  = (float*)d_out;                       // [N]
    float* out_xe = out_y + NROWS;                       // [N, 512]
    float* out_t  = out_xe + (size_t)NROWS * 512;        // [N]

    // ---- choose row-chunk size R from ws_size (deterministic per process) ----
    // Chunk buffers are ALIASED by lifetime (disjoint within the stream order):
    //   bufA: xbc (cvt->L0) then h2c (L1->L2)      : 4096 B/row
    //   bufB: h1c (L0->L1)  then g1c (Ey0->Ey1)    : 4096 B/row
    // => 8192 B/row (was 11264), letting the scan reach R=65536/NCHUNK=1 when
    // the workspace allows (halves launch count + dispatch tails).
    const size_t FIXED = ((size_t)(2048 * 512 + 2048 * 2048 + 512 * 2048
                          + TTREAT * 1024 * 512 + TTREAT * 512 * 1024
                          + (size_t)NROWS * 512) * 2)                 // bf16 bufs
                          + (size_t)TTREAT * NROWS * 4 + (1 << 20);   // idx + slack
    int R = 512;
    const int cands[8] = {65536, 32768, 16384, 8192, 4096, 2048, 1024, 512};
    for (int ci = 0; ci < 8; ++ci) {
        if (FIXED + (size_t)cands[ci] * 8192 <= ws_size) { R = cands[ci]; break; }
    }
    const int NCHUNK = NROWS / R;

    // ---- workspace carve-up ----
    size_t off = 0;
    auto carve = [&](size_t bytes) {
        void* p = (char*)d_ws + off;
        off += (bytes + 255) & ~(size_t)255;
        return p;
    };
    u16* Wx0t = (u16*)carve((size_t)2048 * 512 * 2);
    u16* Wx1t = (u16*)carve((size_t)2048 * 2048 * 2);
    u16* Wx2t = (u16*)carve((size_t)512 * 2048 * 2);
    u16* Wy0t = (u16*)carve((size_t)TTREAT * 1024 * 512 * 2);
    u16* Wy1t = (u16*)carve((size_t)TTREAT * 512 * 1024 * 2);
    u16* xe   = (u16*)carve((size_t)NROWS * 512 * 2);        // full-N bf16 x_emb
    int* idx  = (int*)carve((size_t)TTREAT * NROWS * 4);
    int* cnt  = (int*)carve(256);
    u16* bufA = (u16*)carve((size_t)R * 4096);               // xbc | h2c
    u16* bufB = (u16*)carve((size_t)R * 4096);               // h1c | g1c
    u16* xbc = bufA;   // [R,512]  bf16, live cvt -> L0
    u16* h2c = bufA;   // [R,2048] bf16, live L1  -> L2 (xbc dead by then)
    u16* h1c = bufB;   // [R,2048] bf16, live L0  -> L1
    u16* g1c = bufB;   // [R,1024] bf16, live Ey0 -> Ey1 (h1c dead: trunk done)

    dim3 tb32(32, 8);

    // weight transposes (bf16, [M,K], swizzled) — once
    transpose_w<<<dim3(2048 / 32, 512 / 32, 1), tb32, 0, stream>>>(Wx0, Wx0t, 512, 2048);
    transpose_w<<<dim3(2048 / 32, 2048 / 32, 1), tb32, 0, stream>>>(Wx1, Wx1t, 2048, 2048);
    transpose_w<<<dim3(512 / 32, 2048 / 32, 1), tb32, 0, stream>>>(Wx2, Wx2t, 2048, 512);
    transpose_w<<<dim3(1024 / 32, 512 / 32, TTREAT), tb32, 0, stream>>>(Wy0, Wy0t, 512, 1024);
    transpose_w<<<dim3(512 / 32, 1024 / 32, TTREAT), tb32, 0, stream>>>(Wy1, Wy1t, 1024, 512);

    // partition rows by treatment — once
    zero_cnt<<<1, 64, 0, stream>>>(cnt);
    partition_rows<<<NROWS / 256, 256, 0, stream>>>(treat, idx, cnt);

    // output init (y = head bias, t_out = 1.0)
    init_outputs<<<NROWS / 256, 256, 0, stream>>>(treat, bo, out_y, out_t);

    const int gy = R / 128;   // chunk-local row blocks

    // ---- trunk, chunked over rows ----
    for (int c = 0; c < NCHUNK; ++c) {
        int cS = c * R;
        cvt_f32_bf16<<<(R * 512 / 8 + 255) / 256, 256, 0, stream>>>(
            (const float4*)(x + (size_t)cS * 512), (u16x8*)xbc, R * 512 / 8);
        gemm_bias_relu<false, false, false><<<dim3(2048 / 128, gy), 256, 0, stream>>>(
            xbc, Wx0t, bx0, h1c, nullptr, nullptr, nullptr, NROWS, cS, R, 512, 2048,
            nullptr, nullptr);
        gemm_bias_relu<false, false, false><<<dim3(2048 / 128, gy), 256, 0, stream>>>(
            h1c, Wx1t, bx1, h2c, nullptr, nullptr, nullptr, NROWS, cS, R, 2048, 2048,
            nullptr, nullptr);
        gemm_bias_relu<false, true, false><<<dim3(512 / 128, gy), 256, 0, stream>>>(
            h2c, Wx2t, bx2, xe + (size_t)cS * 512, out_xe + (size_t)cS * 512,
            nullptr, nullptr, NROWS, cS, R, 2048, 512, nullptr, nullptr);
    }

    // ---- experts (only the selected treatment's rows), chunked ----
    for (int t = 0; t < TTREAT; ++t) {
        const int* idx_t = idx + (size_t)t * NROWS;
        for (int c = 0; c < NCHUNK; ++c) {
            int cS = c * R;
            gemm_bias_relu<true, false, false><<<dim3(1024 / 128, gy), 256, 0, stream>>>(
                xe, Wy0t + (size_t)t * 1024 * 512, by0 + (size_t)t * 1024,
                g1c, nullptr, idx_t + cS, cnt + t, NROWS, cS, R, 512, 1024,
                nullptr, nullptr);
            // expert layer 1 with fused output head (no C write; atomic dots)
            gemm_bias_relu<false, false, true><<<dim3(512 / 128, gy), 256, 0, stream>>>(
                g1c, Wy1t + (size_t)t * 512 * 1024, by1 + (size_t)t * 512,
                nullptr, nullptr, idx_t + cS, cnt + t, NROWS, cS, R, 1024, 512,
                Wo + (size_t)t * 512, out_y);
        }
    }
}